// Round 6
// baseline (427.982 us; speedup 1.0000x reference)
//
#include <hip/hip_runtime.h>

#define NS 64
#define HH 64
#define WW 64
#define VD 64
#define VH 64
#define VW 64
#define NVOX (VD*VH*VW)
#define NPIX (NS*HH*WW)
#define RES 1.5f
#define NTAB (NS*27)
#define WIN 6

// ---------------------------------------------------------------
// Per-(slice,tap) affine table:  pos = w*U + h*V + C
// entry layout (16 floats):
//  [0..3]  a,b,c,d   : inverse of [[Ux,Vx],[Uy,Vy]]
//  [4..7]  Ux,Uy,Uz,Vx
//  [8..11] Vy,Vz,Cx,Cy
//  [12..15]Cz,psf_k,0,0
// ---------------------------------------------------------------
__global__ __launch_bounds__(256) void k_setup(const float* __restrict__ tr,
                                               const float* __restrict__ psf,
                                               float* __restrict__ tab) {
    int i = blockIdx.x * 256 + threadIdx.x;
    if (i >= NTAB) return;
    int s = i / 27, k = i % 27;
    const float* p = tr + s * 12;
    float R00 = p[0], R01 = p[1], R02 = p[2],  t0 = p[3];
    float R10 = p[4], R11 = p[5], R12 = p[6],  t1 = p[7];
    float R20 = p[8], R21 = p[9], R22 = p[10], t2 = p[11];
    float Ux = RES * R00, Uy = RES * R10, Uz = RES * R20;
    float Vx = RES * R01, Vy = RES * R11, Vz = RES * R21;
    float ox = (float)(k % 3 - 1), oy = (float)((k / 3) % 3 - 1), oz = (float)(k / 9 - 1);
    float Cx = t0 + 31.5f + R00 * ox + R01 * oy + R02 * oz - 31.5f * (Ux + Vx);
    float Cy = t1 + 31.5f + R10 * ox + R11 * oy + R12 * oz - 31.5f * (Uy + Vy);
    float Cz = t2 + 31.5f + R20 * ox + R21 * oy + R22 * oz - 31.5f * (Uz + Vz);
    float inv = 1.f / (Ux * Vy - Uy * Vx);
    float* e = tab + i * 16;
    e[0] = Vy * inv;  e[1] = -Vx * inv; e[2] = -Uy * inv; e[3] = Ux * inv;
    e[4] = Ux; e[5] = Uy; e[6] = Uz; e[7] = Vx;
    e[8] = Vy; e[9] = Vz; e[10] = Cx; e[11] = Cy;
    e[12] = Cz; e[13] = psf[k]; e[14] = 0.f; e[15] = 0.f;
}

// ---------------------------------------------------------------
// Branch-free trilinear gather: clamped addresses, zeroed weights.
// ---------------------------------------------------------------
__device__ __forceinline__ float trilin_gather_bf(const float* __restrict__ vol,
                                                  float px, float py, float pz) {
    float x0 = floorf(px), y0 = floorf(py), z0 = floorf(pz);
    float fx = px - x0, fy = py - y0, fz = pz - z0;
    int ix = (int)x0, iy = (int)y0, iz = (int)z0;

    float wx0 = ((unsigned)ix       < 64u) ? (1.f - fx) : 0.f;
    float wx1 = ((unsigned)(ix + 1) < 64u) ? fx         : 0.f;
    float wy0 = ((unsigned)iy       < 64u) ? (1.f - fy) : 0.f;
    float wy1 = ((unsigned)(iy + 1) < 64u) ? fy         : 0.f;
    float wz0 = ((unsigned)iz       < 64u) ? (1.f - fz) : 0.f;
    float wz1 = ((unsigned)(iz + 1) < 64u) ? fz         : 0.f;

    int xc0 = min(max(ix, 0), 63),     xc1 = min(max(ix + 1, 0), 63);
    int yc0 = min(max(iy, 0), 63) << 6,  yc1 = min(max(iy + 1, 0), 63) << 6;
    int zc0 = min(max(iz, 0), 63) << 12, zc1 = min(max(iz + 1, 0), 63) << 12;

    float v000 = vol[zc0 + yc0 + xc0], v001 = vol[zc0 + yc0 + xc1];
    float v010 = vol[zc0 + yc1 + xc0], v011 = vol[zc0 + yc1 + xc1];
    float v100 = vol[zc1 + yc0 + xc0], v101 = vol[zc1 + yc0 + xc1];
    float v110 = vol[zc1 + yc1 + xc0], v111 = vol[zc1 + yc1 + xc1];

    float w00 = wx0 * wy0, w01 = wx1 * wy0, w10 = wx0 * wy1, w11 = wx1 * wy1;
    float lo = fmaf(w00, v000, fmaf(w01, v001, fmaf(w10, v010, w11 * v011)));
    float hi = fmaf(w00, v100, fmaf(w01, v101, fmaf(w10, v110, w11 * v111)));
    return fmaf(wz0, lo, wz1 * hi);
}

// ---------------------------------------------------------------
// Forward projection A: 4 lanes per pixel, taps k = q + 4*j.
// grid = NPIX*4/256 = 4096 blocks.
// ---------------------------------------------------------------
__global__ __launch_bounds__(256) void k_a(const float* __restrict__ vin,
                                           float* __restrict__ g,
                                           const float* __restrict__ tr,
                                           const float* __restrict__ psf) {
    __shared__ float s_psf[27];
    if (threadIdx.x < 27) s_psf[threadIdx.x] = psf[threadIdx.x];
    __syncthreads();
    int gid = blockIdx.x * 256 + threadIdx.x;
    int pixel = gid >> 2, q = gid & 3;
    int s = pixel >> 12;
    int pix = pixel & 4095;
    int h = pix >> 6, w = pix & 63;
    const float* p = tr + s * 12;
    float R0 = p[0], R1 = p[1], R2 = p[2],  t0 = p[3];
    float R3 = p[4], R4 = p[5], R5 = p[6],  t1 = p[7];
    float R6 = p[8], R7 = p[9], R8 = p[10], t2 = p[11];
    float xs = ((float)w - 31.5f) * RES;
    float ys = ((float)h - 31.5f) * RES;
    float p0x = fmaf(R0, xs, fmaf(R1, ys, t0)) + 31.5f;
    float p0y = fmaf(R3, xs, fmaf(R4, ys, t1)) + 31.5f;
    float p0z = fmaf(R6, xs, fmaf(R7, ys, t2)) + 31.5f;
    float a = 0.f;
#pragma unroll
    for (int j = 0; j < 7; ++j) {
        int k = q + 4 * j;
        if (k < 27) {
            float ox = (float)(k % 3 - 1), oy = (float)((k / 3) % 3 - 1), oz = (float)(k / 9 - 1);
            float px = p0x + ox * R0 + oy * R1 + oz * R2;
            float py = p0y + ox * R3 + oy * R4 + oz * R5;
            float pz = p0z + ox * R6 + oy * R7 + oz * R8;
            a = fmaf(s_psf[k], trilin_gather_bf(vin, px, py, pz), a);
        }
    }
    a += __shfl_xor(a, 1);
    a += __shfl_xor(a, 2);
    if (q == 0) g[pixel] = a;
}

// ---------------- block reduce -> one atomic ----------------
__device__ __forceinline__ void block_reduce_atomic(float v, float* dst) {
#pragma unroll
    for (int off = 32; off > 0; off >>= 1) v += __shfl_down(v, off, 64);
    __shared__ float s_red[4];
    int lane = threadIdx.x & 63, wid = threadIdx.x >> 6;
    if (lane == 0) s_red[wid] = v;
    __syncthreads();
    if (threadIdx.x == 0) atomicAdd(dst, s_red[0] + s_red[1] + s_red[2] + s_red[3]);
}

// ---------------------------------------------------------------
// Adjoint At: gather over voxel columns, 6-wide register z-window.
// Block = 2 columns x 64 slices x 2 tap-halves (k = half + 2j).
// grid = 4096/2 = 2048 blocks -> 8 blocks/CU (full wave occupancy).
// MODE 0: vout = At(g)
// MODE 1: rv = aux - At(g); r = p = rv; scal += rr       (residual)
// MODE 2: vout = At(g); scal += dot(aux, vout)           (p.Ap)
// ---------------------------------------------------------------
template<int MODE>
__global__ __launch_bounds__(256, 8) void k_atv(const float* __restrict__ g,
                                                float* __restrict__ vout,
                                                const float* __restrict__ tab,
                                                const float* __restrict__ aux,
                                                float* __restrict__ r,
                                                float* __restrict__ p,
                                                float* __restrict__ scal_dst) {
    __shared__ float cols[2][68];
    for (int i = threadIdx.x; i < 2 * 68; i += 256) (&cols[0][0])[i] = 0.f;
    __syncthreads();

    int lc   = threadIdx.x & 1;         // column within block
    int half = (threadIdx.x >> 1) & 1;  // tap parity
    int s    = threadIdx.x >> 2;        // 0..63
    int col0 = blockIdx.x * 2;
    int col  = col0 + lc;
    float X = (float)(col & 63), Y = (float)(col >> 6);

    const float* tbase = tab + s * 27 * 16;
    int gbase = s << 12;

    // window base from center tap (k=13, ox=oy=oz=0)
    const float* ec = tbase + 13 * 16;
    float4 c0 = *(const float4*)(ec);
    float4 c1 = *(const float4*)(ec + 4);
    float4 c2 = *(const float4*)(ec + 8);
    float4 c3 = *(const float4*)(ec + 12);
    float rxc = X - c2.z, ryc = Y - c2.w;
    float wsc = c0.x * rxc + c0.y * ryc;
    float hsc = c0.z * rxc + c0.w * ryc;
    float pzc = fmaf(wsc, c1.z, fmaf(hsc, c2.y, c3.x));
    float basef = floorf(pzc) - 2.f;
    int   basei = (int)basef;

    float acc[WIN];
#pragma unroll
    for (int j = 0; j < WIN; ++j) acc[j] = 0.f;

#pragma unroll 2
    for (int jk = 0; jk < 14; ++jk) {
        int k = half + 2 * jk;
        if (k < 27) {
            const float* e = tbase + k * 16;
            float4 e0 = *(const float4*)(e);
            float4 e1 = *(const float4*)(e + 4);
            float4 e2 = *(const float4*)(e + 8);
            float4 e3 = *(const float4*)(e + 12);
            float Ux = e1.x, Uy = e1.y, Uz = e1.z, Vx = e1.w;
            float Vy = e2.x, Vz = e2.y;
            float Cxr = e2.z - X, Cyr = e2.w - Y;   // C - voxel(x,y)
            float psfk = e3.y;
            float ws = e0.x * (-Cxr) + e0.y * (-Cyr);
            float hs = e0.z * (-Cxr) + e0.w * (-Cyr);
            float w0f = floorf(ws), h0f = floorf(hs);
            int w0 = (int)w0f, h0 = (int)h0f;
#pragma unroll
            for (int dh = 0; dh < 2; ++dh) {
                float fh = h0f + (float)dh;
                int hi = h0 + dh;
                int hok = ((unsigned)hi < 64u) ? 1 : 0;
                int hc = min(max(hi, 0), 63);
                float tx = fmaf(fh, Vx, Cxr);
                float ty = fmaf(fh, Vy, Cyr);
                float tz = fmaf(fh, Vz, e3.x);
#pragma unroll
                for (int dw = 0; dw < 2; ++dw) {
                    float fw = w0f + (float)dw;
                    int wi = w0 + dw;
                    int ok = ((unsigned)wi < 64u) ? hok : 0;
                    int wc = min(max(wi, 0), 63);
                    float ddx = fmaf(fw, Ux, tx);          // px - X
                    float ddy = fmaf(fw, Uy, ty);          // py - Y
                    float wx = fmaxf(0.f, 1.f - fabsf(ddx));
                    float wy = fmaxf(0.f, 1.f - fabsf(ddy));
                    float gv = g[gbase + (hc << 6) + wc];
                    float val = ok ? (wx * wy * psfk * gv) : 0.f;
                    float prel = fmaf(fw, Uz, tz) - basef; // pz - base
#pragma unroll
                    for (int j = 0; j < WIN; ++j) {
                        float t = fmaxf(0.f, 1.f - fabsf(prel - (float)j));
                        acc[j] = fmaf(val, t, acc[j]);
                    }
                }
            }
        }
    }

#pragma unroll
    for (int j = 0; j < WIN; ++j) {
        int zj = basei + j;
        int okz = ((unsigned)zj < 64u);
        int zc = min(max(zj, 0), 63);
        atomicAdd(&cols[lc][zc], okz ? acc[j] : 0.f);
    }
    __syncthreads();

    // fused epilogue: threads 0..127 own the block's 2x64 voxels
    float contrib = 0.f;
    if (threadIdx.x < 128) {
        int z  = threadIdx.x >> 1;
        int l2 = threadIdx.x & 1;
        int idx = (z << 12) + col0 + l2;
        float v = cols[l2][z];
        if (MODE == 0) {
            vout[idx] = v;
        } else if (MODE == 1) {
            float rv = aux[idx] - v;
            r[idx] = rv;
            p[idx] = rv;
            contrib = rv * rv;
        } else {
            vout[idx] = v;
            contrib = aux[idx] * v;
        }
    }
    if (MODE != 0) block_reduce_atomic(contrib, scal_dst);
}

// ---------------- CG updates ----------------

// alpha = scal[0]/scal[1]; x_out = x_in + alpha p; r -= alpha Ap; scal[2] += r.r
__global__ __launch_bounds__(256) void k_update_xr(const float* __restrict__ x_in,
                                                   float* __restrict__ x_out,
                                                   float* __restrict__ r,
                                                   const float* __restrict__ p,
                                                   const float* __restrict__ Ap,
                                                   float* __restrict__ scal) {
    int i = blockIdx.x * 256 + threadIdx.x;
    float alpha = scal[0] / scal[1];
    x_out[i] = fmaf(alpha, p[i], x_in[i]);
    float rv = fmaf(-alpha, Ap[i], r[i]);
    r[i] = rv;
    block_reduce_atomic(rv * rv, &scal[2]);
}

__global__ __launch_bounds__(256) void k_update_p(float* __restrict__ p,
                                                  const float* __restrict__ r,
                                                  const float* __restrict__ scal) {
    int i = blockIdx.x * 256 + threadIdx.x;
    float beta = scal[2] / scal[0];
    p[i] = fmaf(beta, p[i], r[i]);
}

__global__ __launch_bounds__(256) void k_final(const float* __restrict__ x,
                                               const float* __restrict__ p,
                                               const float* __restrict__ scal,
                                               float* __restrict__ out) {
    int i = blockIdx.x * 256 + threadIdx.x;
    float alpha = scal[2] / scal[3];
    float v = fmaf(alpha, p[i], x[i]);
    out[i] = v > 0.f ? v : 0.f;
}

extern "C" void kernel_launch(void* const* d_in, const int* in_sizes, int n_in,
                              void* d_out, int out_size, void* d_ws, size_t ws_size,
                              hipStream_t stream) {
    const float* transforms = (const float*)d_in[0];
    const float* slices     = (const float*)d_in[1];
    const float* volume     = (const float*)d_in[2];
    const float* psf        = (const float*)d_in[3];
    float* out = (float*)d_out;

    float* tab    = (float*)d_ws;             // 1728*16 floats
    float* vol_b  = tab    + NTAB * 16;
    float* vol_x  = vol_b  + NVOX;
    float* vol_r  = vol_x  + NVOX;
    float* vol_p  = vol_r  + NVOX;
    float* vol_Ap = vol_p  + NVOX;
    float* gbuf   = vol_Ap + NVOX;
    float* scal   = gbuf   + NPIX;            // 4 floats: rr0, pAp0, rr1, pAp1

    const int ablk = (NVOX / 64) / 2;         // 2048 (k_atv: 2 cols/block)
    const int fblk = NPIX * 4 / 256;          // 4096 (k_a: 4 lanes/pixel)
    const int vblk = NVOX / 256;              // 16

    hipMemsetAsync(scal, 0, 4 * sizeof(float), stream);

    k_setup<<<(NTAB + 255) / 256, 256, 0, stream>>>(transforms, psf, tab);

    // b = At(slices)
    k_atv<0><<<ablk, 256, 0, stream>>>(slices, vol_b, tab, nullptr, nullptr, nullptr, nullptr);

    // r = b - AtA(x0); p = r; rr0   (residual fused into adjoint)
    k_a<<<fblk, 256, 0, stream>>>(volume, gbuf, transforms, psf);
    k_atv<1><<<ablk, 256, 0, stream>>>(gbuf, nullptr, tab, vol_b, vol_r, vol_p, &scal[0]);

    // iter 0: Ap = AtA(p); pAp0 fused
    k_a<<<fblk, 256, 0, stream>>>(vol_p, gbuf, transforms, psf);
    k_atv<2><<<ablk, 256, 0, stream>>>(gbuf, vol_Ap, tab, vol_p, nullptr, nullptr, &scal[1]);
    k_update_xr<<<vblk, 256, 0, stream>>>(volume, vol_x, vol_r, vol_p, vol_Ap, scal);
    k_update_p<<<vblk, 256, 0, stream>>>(vol_p, vol_r, scal);

    // iter 1: pAp1 fused
    k_a<<<fblk, 256, 0, stream>>>(vol_p, gbuf, transforms, psf);
    k_atv<2><<<ablk, 256, 0, stream>>>(gbuf, vol_Ap, tab, vol_p, nullptr, nullptr, &scal[3]);
    k_final<<<vblk, 256, 0, stream>>>(vol_x, vol_p, scal, out);
}

// Round 7
// 334.925 us; speedup vs baseline: 1.2778x; 1.2778x over previous
//
#include <hip/hip_runtime.h>

#define NS 64
#define HH 64
#define WW 64
#define VD 64
#define VH 64
#define VW 64
#define NVOX (VD*VH*VW)
#define NPIX (NS*HH*WW)
#define RES 1.5f
#define NTAB (NS*27)
#define WIN 6
#define SPLIT 8
#define SLC_PER 8              // slices per block = waves per block
#define COL_PAD 67

// ---------------------------------------------------------------
// Per-(slice,tap) affine table:  pos = w*U + h*V + C
// entry layout (16 floats):
//  [0..3]  a,b,c,d   : inverse of [[Ux,Vx],[Uy,Vy]]
//  [4..7]  Ux,Uy,Uz,Vx
//  [8..11] Vy,Vz,Cx,Cy
//  [12..15]Cz,psf_k,0,0
// ---------------------------------------------------------------
__global__ __launch_bounds__(256) void k_setup(const float* __restrict__ tr,
                                               const float* __restrict__ psf,
                                               float* __restrict__ tab) {
    int i = blockIdx.x * 256 + threadIdx.x;
    if (i >= NTAB) return;
    int s = i / 27, k = i % 27;
    const float* p = tr + s * 12;
    float R00 = p[0], R01 = p[1], R02 = p[2],  t0 = p[3];
    float R10 = p[4], R11 = p[5], R12 = p[6],  t1 = p[7];
    float R20 = p[8], R21 = p[9], R22 = p[10], t2 = p[11];
    float Ux = RES * R00, Uy = RES * R10, Uz = RES * R20;
    float Vx = RES * R01, Vy = RES * R11, Vz = RES * R21;
    float ox = (float)(k % 3 - 1), oy = (float)((k / 3) % 3 - 1), oz = (float)(k / 9 - 1);
    float Cx = t0 + 31.5f + R00 * ox + R01 * oy + R02 * oz - 31.5f * (Ux + Vx);
    float Cy = t1 + 31.5f + R10 * ox + R11 * oy + R12 * oz - 31.5f * (Uy + Vy);
    float Cz = t2 + 31.5f + R20 * ox + R21 * oy + R22 * oz - 31.5f * (Uz + Vz);
    float inv = 1.f / (Ux * Vy - Uy * Vx);
    float* e = tab + i * 16;
    e[0] = Vy * inv;  e[1] = -Vx * inv; e[2] = -Uy * inv; e[3] = Ux * inv;
    e[4] = Ux; e[5] = Uy; e[6] = Uz; e[7] = Vx;
    e[8] = Vy; e[9] = Vz; e[10] = Cx; e[11] = Cy;
    e[12] = Cz; e[13] = psf[k]; e[14] = 0.f; e[15] = 0.f;
}

// ---------------------------------------------------------------
// Branch-free trilinear gather: clamped addresses, zeroed weights.
// ---------------------------------------------------------------
__device__ __forceinline__ float trilin_gather_bf(const float* __restrict__ vol,
                                                  float px, float py, float pz) {
    float x0 = floorf(px), y0 = floorf(py), z0 = floorf(pz);
    float fx = px - x0, fy = py - y0, fz = pz - z0;
    int ix = (int)x0, iy = (int)y0, iz = (int)z0;

    float wx0 = ((unsigned)ix       < 64u) ? (1.f - fx) : 0.f;
    float wx1 = ((unsigned)(ix + 1) < 64u) ? fx         : 0.f;
    float wy0 = ((unsigned)iy       < 64u) ? (1.f - fy) : 0.f;
    float wy1 = ((unsigned)(iy + 1) < 64u) ? fy         : 0.f;
    float wz0 = ((unsigned)iz       < 64u) ? (1.f - fz) : 0.f;
    float wz1 = ((unsigned)(iz + 1) < 64u) ? fz         : 0.f;

    int xc0 = min(max(ix, 0), 63),     xc1 = min(max(ix + 1, 0), 63);
    int yc0 = min(max(iy, 0), 63) << 6,  yc1 = min(max(iy + 1, 0), 63) << 6;
    int zc0 = min(max(iz, 0), 63) << 12, zc1 = min(max(iz + 1, 0), 63) << 12;

    float v000 = vol[zc0 + yc0 + xc0], v001 = vol[zc0 + yc0 + xc1];
    float v010 = vol[zc0 + yc1 + xc0], v011 = vol[zc0 + yc1 + xc1];
    float v100 = vol[zc1 + yc0 + xc0], v101 = vol[zc1 + yc0 + xc1];
    float v110 = vol[zc1 + yc1 + xc0], v111 = vol[zc1 + yc1 + xc1];

    float w00 = wx0 * wy0, w01 = wx1 * wy0, w10 = wx0 * wy1, w11 = wx1 * wy1;
    float lo = fmaf(w00, v000, fmaf(w01, v001, fmaf(w10, v010, w11 * v011)));
    float hi = fmaf(w00, v100, fmaf(w01, v101, fmaf(w10, v110, w11 * v111)));
    return fmaf(wz0, lo, wz1 * hi);
}

// ---------------------------------------------------------------
// Forward projection A: 4 lanes per pixel, taps k = q + 4*j.
// ---------------------------------------------------------------
__global__ __launch_bounds__(256) void k_a(const float* __restrict__ vin,
                                           float* __restrict__ g,
                                           const float* __restrict__ tr,
                                           const float* __restrict__ psf) {
    __shared__ float s_psf[27];
    if (threadIdx.x < 27) s_psf[threadIdx.x] = psf[threadIdx.x];
    __syncthreads();
    int gid = blockIdx.x * 256 + threadIdx.x;
    int pixel = gid >> 2, q = gid & 3;
    int s = pixel >> 12;
    int pix = pixel & 4095;
    int h = pix >> 6, w = pix & 63;
    const float* p = tr + s * 12;
    float R0 = p[0], R1 = p[1], R2 = p[2],  t0 = p[3];
    float R3 = p[4], R4 = p[5], R5 = p[6],  t1 = p[7];
    float R6 = p[8], R7 = p[9], R8 = p[10], t2 = p[11];
    float xs = ((float)w - 31.5f) * RES;
    float ys = ((float)h - 31.5f) * RES;
    float p0x = fmaf(R0, xs, fmaf(R1, ys, t0)) + 31.5f;
    float p0y = fmaf(R3, xs, fmaf(R4, ys, t1)) + 31.5f;
    float p0z = fmaf(R6, xs, fmaf(R7, ys, t2)) + 31.5f;
    float a = 0.f;
#pragma unroll
    for (int j = 0; j < 7; ++j) {
        int k = q + 4 * j;
        if (k < 27) {
            float ox = (float)(k % 3 - 1), oy = (float)((k / 3) % 3 - 1), oz = (float)(k / 9 - 1);
            float px = p0x + ox * R0 + oy * R1 + oz * R2;
            float py = p0y + ox * R3 + oy * R4 + oz * R5;
            float pz = p0z + ox * R6 + oy * R7 + oz * R8;
            a = fmaf(s_psf[k], trilin_gather_bf(vin, px, py, pz), a);
        }
    }
    a += __shfl_xor(a, 1);
    a += __shfl_xor(a, 2);
    if (q == 0) g[pixel] = a;
}

// ---------------- block reduce -> one atomic (256-thr kernels) ----------------
__device__ __forceinline__ void block_reduce_atomic(float v, float* dst) {
#pragma unroll
    for (int off = 32; off > 0; off >>= 1) v += __shfl_down(v, off, 64);
    __shared__ float s_red[4];
    int lane = threadIdx.x & 63, wid = threadIdx.x >> 6;
    if (lane == 0) s_red[wid] = v;
    __syncthreads();
    if (threadIdx.x == 0) atomicAdd(dst, s_red[0] + s_red[1] + s_red[2] + s_red[3]);
}

// ---------------------------------------------------------------
// Adjoint At: LDS-staged table, one y-row of 64 columns per block.
// Block = 512 threads = 64 cols (lane) x 8 slices (wave).
// blockIdx: y = b >> 3 (64 rows), split = b & 7 (slices split*8+wave).
// Table slab (8 slices x 27 taps) staged to LDS once -> all tap reads
// are same-address LDS broadcasts. Writes partial volume per split.
// ---------------------------------------------------------------
__global__ __launch_bounds__(512, 4) void k_atv(const float* __restrict__ g,
                                                float* __restrict__ part,
                                                const float* __restrict__ tab) {
    __shared__ float stab[SLC_PER * 27 * 16];   // 13.8 KB
    __shared__ float cols[64][COL_PAD];         // 17.2 KB

    int tid = threadIdx.x;
    int Yb = blockIdx.x >> 3;
    int split = blockIdx.x & 7;

    // stage table slab (coalesced float4)
    {
        const float4* src = (const float4*)(tab + split * SLC_PER * 27 * 16);
        float4* dst = (float4*)stab;
#pragma unroll
        for (int i = 0; i < 2; ++i) {
            int j = tid + i * 512;
            if (j < SLC_PER * 27 * 4) dst[j] = src[j];
        }
    }
    // zero accumulators
    {
        float4* c4 = (float4*)&cols[0][0];
        // 64*67 = 4288 floats; pad tail handled: 4288/4 = 1072 float4
#pragma unroll
        for (int i = 0; i < 3; ++i) {
            int j = tid + i * 512;
            if (j < 1072) c4[j] = make_float4(0.f, 0.f, 0.f, 0.f);
        }
    }
    __syncthreads();

    int lane = tid & 63;                 // x
    int wave = tid >> 6;                 // 0..7
    int s = split * SLC_PER + wave;      // global slice
    float X = (float)lane, Y = (float)Yb;

    const float* tb = stab + wave * 27 * 16;
    int gbase = s << 12;

    // window base from center tap (k=13)
    const float* ec = tb + 13 * 16;
    float4 c0 = *(const float4*)(ec);
    float4 c1 = *(const float4*)(ec + 4);
    float4 c2 = *(const float4*)(ec + 8);
    float4 c3 = *(const float4*)(ec + 12);
    float rxc = X - c2.z, ryc = Y - c2.w;
    float wsc = c0.x * rxc + c0.y * ryc;
    float hsc = c0.z * rxc + c0.w * ryc;
    float pzc = fmaf(wsc, c1.z, fmaf(hsc, c2.y, c3.x));
    float basef = floorf(pzc) - 2.f;
    int   basei = (int)basef;

    float acc[WIN];
#pragma unroll
    for (int j = 0; j < WIN; ++j) acc[j] = 0.f;

    for (int k = 0; k < 27; ++k) {
        const float* e = tb + k * 16;
        float4 e0 = *(const float4*)(e);
        float4 e1 = *(const float4*)(e + 4);
        float4 e2 = *(const float4*)(e + 8);
        float4 e3 = *(const float4*)(e + 12);
        float Ux = e1.x, Uy = e1.y, Uz = e1.z, Vx = e1.w;
        float Vy = e2.x, Vz = e2.y;
        float Cxr = e2.z - X, Cyr = e2.w - Y;   // C - voxel(x,y)
        float psfk = e3.y;
        float ws = e0.x * (-Cxr) + e0.y * (-Cyr);
        float hs = e0.z * (-Cxr) + e0.w * (-Cyr);
        float w0f = floorf(ws), h0f = floorf(hs);
        int w0 = (int)w0f, h0 = (int)h0f;
#pragma unroll
        for (int dh = 0; dh < 2; ++dh) {
            float fh = h0f + (float)dh;
            int hi = h0 + dh;
            int hok = ((unsigned)hi < 64u) ? 1 : 0;
            int hc = min(max(hi, 0), 63);
            float tx = fmaf(fh, Vx, Cxr);
            float ty = fmaf(fh, Vy, Cyr);
            float tz = fmaf(fh, Vz, e3.x);
#pragma unroll
            for (int dw = 0; dw < 2; ++dw) {
                float fw = w0f + (float)dw;
                int wi = w0 + dw;
                int ok = ((unsigned)wi < 64u) ? hok : 0;
                int wc = min(max(wi, 0), 63);
                float ddx = fmaf(fw, Ux, tx);          // px - X
                float ddy = fmaf(fw, Uy, ty);          // py - Y
                float wx = fmaxf(0.f, 1.f - fabsf(ddx));
                float wy = fmaxf(0.f, 1.f - fabsf(ddy));
                float gv = g[gbase + (hc << 6) + wc];
                float val = ok ? (wx * wy * psfk * gv) : 0.f;
                float prel = fmaf(fw, Uz, tz) - basef; // pz - base
#pragma unroll
                for (int j = 0; j < WIN; ++j) {
                    float t = fmaxf(0.f, 1.f - fabsf(prel - (float)j));
                    acc[j] = fmaf(val, t, acc[j]);
                }
            }
        }
    }

#pragma unroll
    for (int j = 0; j < WIN; ++j) {
        int zj = basei + j;
        int okz = ((unsigned)zj < 64u);
        int zc = min(max(zj, 0), 63);
        atomicAdd(&cols[lane][zc], okz ? acc[j] : 0.f);
    }
    __syncthreads();

    // write partial: 4096 voxels of this y-row
    float* pout = part + split * NVOX + (Yb << 6);
#pragma unroll
    for (int i = 0; i < 8; ++i) {
        int j = tid + i * 512;           // j < 4096
        int z = j >> 6, x = j & 63;
        pout[(z << 12) + x] = cols[x][z];
    }
}

// ---------------- partial-sum consumers & CG updates ----------------

__device__ __forceinline__ float sum8(const float* __restrict__ part, int i) {
    float a = 0.f;
#pragma unroll
    for (int j = 0; j < SPLIT; ++j) a += part[j * NVOX + i];
    return a;
}

// vol_b = sum8(part)
__global__ __launch_bounds__(256) void k_sum8(const float* __restrict__ part,
                                              float* __restrict__ vout) {
    int i = blockIdx.x * 256 + threadIdx.x;
    vout[i] = sum8(part, i);
}

// rv = b - sum8(part); r = p = rv; scal += rr
__global__ __launch_bounds__(256) void k_residual8(const float* __restrict__ b,
                                                   const float* __restrict__ part,
                                                   float* __restrict__ r,
                                                   float* __restrict__ p,
                                                   float* __restrict__ scal) {
    int i = blockIdx.x * 256 + threadIdx.x;
    float rv = b[i] - sum8(part, i);
    r[i] = rv;
    p[i] = rv;
    block_reduce_atomic(rv * rv, &scal[0]);
}

// Ap = sum8(part); scal += p.Ap
__global__ __launch_bounds__(256) void k_dot_reduce8(const float* __restrict__ part,
                                                     const float* __restrict__ p,
                                                     float* __restrict__ Ap,
                                                     float* __restrict__ dst) {
    int i = blockIdx.x * 256 + threadIdx.x;
    float apv = sum8(part, i);
    Ap[i] = apv;
    block_reduce_atomic(p[i] * apv, dst);
}

// scal += p . sum8(part)
__global__ __launch_bounds__(256) void k_dot8(const float* __restrict__ part,
                                              const float* __restrict__ p,
                                              float* __restrict__ dst) {
    int i = blockIdx.x * 256 + threadIdx.x;
    block_reduce_atomic(p[i] * sum8(part, i), dst);
}

// alpha = scal[0]/scal[1]; x_out = x_in + alpha p; r -= alpha Ap; scal[2] += r.r
__global__ __launch_bounds__(256) void k_update_xr(const float* __restrict__ x_in,
                                                   float* __restrict__ x_out,
                                                   float* __restrict__ r,
                                                   const float* __restrict__ p,
                                                   const float* __restrict__ Ap,
                                                   float* __restrict__ scal) {
    int i = blockIdx.x * 256 + threadIdx.x;
    float alpha = scal[0] / scal[1];
    x_out[i] = fmaf(alpha, p[i], x_in[i]);
    float rv = fmaf(-alpha, Ap[i], r[i]);
    r[i] = rv;
    block_reduce_atomic(rv * rv, &scal[2]);
}

__global__ __launch_bounds__(256) void k_update_p(float* __restrict__ p,
                                                  const float* __restrict__ r,
                                                  const float* __restrict__ scal) {
    int i = blockIdx.x * 256 + threadIdx.x;
    float beta = scal[2] / scal[0];
    p[i] = fmaf(beta, p[i], r[i]);
}

__global__ __launch_bounds__(256) void k_final(const float* __restrict__ x,
                                               const float* __restrict__ p,
                                               const float* __restrict__ scal,
                                               float* __restrict__ out) {
    int i = blockIdx.x * 256 + threadIdx.x;
    float alpha = scal[2] / scal[3];
    float v = fmaf(alpha, p[i], x[i]);
    out[i] = v > 0.f ? v : 0.f;
}

extern "C" void kernel_launch(void* const* d_in, const int* in_sizes, int n_in,
                              void* d_out, int out_size, void* d_ws, size_t ws_size,
                              hipStream_t stream) {
    const float* transforms = (const float*)d_in[0];
    const float* slices     = (const float*)d_in[1];
    const float* volume     = (const float*)d_in[2];
    const float* psf        = (const float*)d_in[3];
    float* out = (float*)d_out;

    float* tab    = (float*)d_ws;             // 1728*16 floats
    float* part   = tab    + NTAB * 16;       // 8 * NVOX (8 MB)
    float* vol_b  = part   + SPLIT * NVOX;
    float* vol_x  = vol_b  + NVOX;
    float* vol_r  = vol_x  + NVOX;
    float* vol_p  = vol_r  + NVOX;
    float* vol_Ap = vol_p  + NVOX;
    float* gbuf   = vol_Ap + NVOX;
    float* scal   = gbuf   + NPIX;            // 4 floats: rr0, pAp0, rr1, pAp1

    const int ablk = 64 * SPLIT;              // 512 (k_atv: y-row x split)
    const int fblk = NPIX * 4 / 256;          // 4096 (k_a: 4 lanes/pixel)
    const int vblk = NVOX / 256;              // 16

    hipMemsetAsync(scal, 0, 4 * sizeof(float), stream);

    k_setup<<<(NTAB + 255) / 256, 256, 0, stream>>>(transforms, psf, tab);

    // b = At(slices)
    k_atv<<<ablk, 512, 0, stream>>>(slices, part, tab);
    k_sum8<<<vblk, 256, 0, stream>>>(part, vol_b);

    // r = b - AtA(x0); p = r; rr0
    k_a<<<fblk, 256, 0, stream>>>(volume, gbuf, transforms, psf);
    k_atv<<<ablk, 512, 0, stream>>>(gbuf, part, tab);
    k_residual8<<<vblk, 256, 0, stream>>>(vol_b, part, vol_r, vol_p, scal);

    // iter 0: Ap = AtA(p)
    k_a<<<fblk, 256, 0, stream>>>(vol_p, gbuf, transforms, psf);
    k_atv<<<ablk, 512, 0, stream>>>(gbuf, part, tab);
    k_dot_reduce8<<<vblk, 256, 0, stream>>>(part, vol_p, vol_Ap, &scal[1]);
    k_update_xr<<<vblk, 256, 0, stream>>>(volume, vol_x, vol_r, vol_p, vol_Ap, scal);
    k_update_p<<<vblk, 256, 0, stream>>>(vol_p, vol_r, scal);

    // iter 1
    k_a<<<fblk, 256, 0, stream>>>(vol_p, gbuf, transforms, psf);
    k_atv<<<ablk, 512, 0, stream>>>(gbuf, part, tab);
    k_dot8<<<vblk, 256, 0, stream>>>(part, vol_p, &scal[3]);
    k_final<<<vblk, 256, 0, stream>>>(vol_x, vol_p, scal, out);
}

// Round 8
// 297.986 us; speedup vs baseline: 1.4362x; 1.1240x over previous
//
#include <hip/hip_runtime.h>

#define NS 64
#define HH 64
#define WW 64
#define VD 64
#define VH 64
#define VW 64
#define NVOX (VD*VH*VW)
#define NPIX (NS*HH*WW)
#define RES 1.5f
#define NTAB (NS*27)
#define WIN 6
#define SPLIT 8
#define COL_PAD 67

// ---------------------------------------------------------------
// Per-(slice,tap) affine table:  pos = w*U + h*V + C
// entry layout (16 floats):
//  [0..3]  a,b,c,d   : inverse of [[Ux,Vx],[Uy,Vy]]
//  [4..7]  Ux,Uy,Uz,Vx
//  [8..11] Vy,Vz,Cx,Cy
//  [12..15]Cz,psf_k,0,0
// ---------------------------------------------------------------
__global__ __launch_bounds__(256) void k_setup(const float* __restrict__ tr,
                                               const float* __restrict__ psf,
                                               float* __restrict__ tab) {
    int i = blockIdx.x * 256 + threadIdx.x;
    if (i >= NTAB) return;
    int s = i / 27, k = i % 27;
    const float* p = tr + s * 12;
    float R00 = p[0], R01 = p[1], R02 = p[2],  t0 = p[3];
    float R10 = p[4], R11 = p[5], R12 = p[6],  t1 = p[7];
    float R20 = p[8], R21 = p[9], R22 = p[10], t2 = p[11];
    float Ux = RES * R00, Uy = RES * R10, Uz = RES * R20;
    float Vx = RES * R01, Vy = RES * R11, Vz = RES * R21;
    float ox = (float)(k % 3 - 1), oy = (float)((k / 3) % 3 - 1), oz = (float)(k / 9 - 1);
    float Cx = t0 + 31.5f + R00 * ox + R01 * oy + R02 * oz - 31.5f * (Ux + Vx);
    float Cy = t1 + 31.5f + R10 * ox + R11 * oy + R12 * oz - 31.5f * (Uy + Vy);
    float Cz = t2 + 31.5f + R20 * ox + R21 * oy + R22 * oz - 31.5f * (Uz + Vz);
    float inv = 1.f / (Ux * Vy - Uy * Vx);
    float* e = tab + i * 16;
    e[0] = Vy * inv;  e[1] = -Vx * inv; e[2] = -Uy * inv; e[3] = Ux * inv;
    e[4] = Ux; e[5] = Uy; e[6] = Uz; e[7] = Vx;
    e[8] = Vy; e[9] = Vz; e[10] = Cx; e[11] = Cy;
    e[12] = Cz; e[13] = psf[k]; e[14] = 0.f; e[15] = 0.f;
}

// ---------------------------------------------------------------
// Branch-free trilinear gather: clamped addresses, zeroed weights.
// ---------------------------------------------------------------
__device__ __forceinline__ float trilin_gather_bf(const float* __restrict__ vol,
                                                  float px, float py, float pz) {
    float x0 = floorf(px), y0 = floorf(py), z0 = floorf(pz);
    float fx = px - x0, fy = py - y0, fz = pz - z0;
    int ix = (int)x0, iy = (int)y0, iz = (int)z0;

    float wx0 = ((unsigned)ix       < 64u) ? (1.f - fx) : 0.f;
    float wx1 = ((unsigned)(ix + 1) < 64u) ? fx         : 0.f;
    float wy0 = ((unsigned)iy       < 64u) ? (1.f - fy) : 0.f;
    float wy1 = ((unsigned)(iy + 1) < 64u) ? fy         : 0.f;
    float wz0 = ((unsigned)iz       < 64u) ? (1.f - fz) : 0.f;
    float wz1 = ((unsigned)(iz + 1) < 64u) ? fz         : 0.f;

    int xc0 = min(max(ix, 0), 63),     xc1 = min(max(ix + 1, 0), 63);
    int yc0 = min(max(iy, 0), 63) << 6,  yc1 = min(max(iy + 1, 0), 63) << 6;
    int zc0 = min(max(iz, 0), 63) << 12, zc1 = min(max(iz + 1, 0), 63) << 12;

    float v000 = vol[zc0 + yc0 + xc0], v001 = vol[zc0 + yc0 + xc1];
    float v010 = vol[zc0 + yc1 + xc0], v011 = vol[zc0 + yc1 + xc1];
    float v100 = vol[zc1 + yc0 + xc0], v101 = vol[zc1 + yc0 + xc1];
    float v110 = vol[zc1 + yc1 + xc0], v111 = vol[zc1 + yc1 + xc1];

    float w00 = wx0 * wy0, w01 = wx1 * wy0, w10 = wx0 * wy1, w11 = wx1 * wy1;
    float lo = fmaf(w00, v000, fmaf(w01, v001, fmaf(w10, v010, w11 * v011)));
    float hi = fmaf(w00, v100, fmaf(w01, v101, fmaf(w10, v110, w11 * v111)));
    return fmaf(wz0, lo, wz1 * hi);
}

// ---------------------------------------------------------------
// Forward projection A: 4 lanes per pixel, taps k = q + 4*j.
// SUB: g = slc - A(vin)   (for r0 = At(slices - A(x0)))
// ---------------------------------------------------------------
template<bool SUB>
__global__ __launch_bounds__(256) void k_a(const float* __restrict__ vin,
                                           float* __restrict__ g,
                                           const float* __restrict__ tr,
                                           const float* __restrict__ psf,
                                           const float* __restrict__ slc) {
    __shared__ float s_psf[27];
    if (threadIdx.x < 27) s_psf[threadIdx.x] = psf[threadIdx.x];
    __syncthreads();
    int gid = blockIdx.x * 256 + threadIdx.x;
    int pixel = gid >> 2, q = gid & 3;
    int s = pixel >> 12;
    int pix = pixel & 4095;
    int h = pix >> 6, w = pix & 63;
    const float* p = tr + s * 12;
    float R0 = p[0], R1 = p[1], R2 = p[2],  t0 = p[3];
    float R3 = p[4], R4 = p[5], R5 = p[6],  t1 = p[7];
    float R6 = p[8], R7 = p[9], R8 = p[10], t2 = p[11];
    float xs = ((float)w - 31.5f) * RES;
    float ys = ((float)h - 31.5f) * RES;
    float p0x = fmaf(R0, xs, fmaf(R1, ys, t0)) + 31.5f;
    float p0y = fmaf(R3, xs, fmaf(R4, ys, t1)) + 31.5f;
    float p0z = fmaf(R6, xs, fmaf(R7, ys, t2)) + 31.5f;
    float a = 0.f;
#pragma unroll
    for (int j = 0; j < 7; ++j) {
        int k = q + 4 * j;
        if (k < 27) {
            float ox = (float)(k % 3 - 1), oy = (float)((k / 3) % 3 - 1), oz = (float)(k / 9 - 1);
            float px = p0x + ox * R0 + oy * R1 + oz * R2;
            float py = p0y + ox * R3 + oy * R4 + oz * R5;
            float pz = p0z + ox * R6 + oy * R7 + oz * R8;
            a = fmaf(s_psf[k], trilin_gather_bf(vin, px, py, pz), a);
        }
    }
    a += __shfl_xor(a, 1);
    a += __shfl_xor(a, 2);
    if (q == 0) g[pixel] = SUB ? (slc[pixel] - a) : a;
}

// ---------------- block reduce -> one atomic (256-thr kernels) ----------------
__device__ __forceinline__ void block_reduce_atomic(float v, float* dst) {
#pragma unroll
    for (int off = 32; off > 0; off >>= 1) v += __shfl_down(v, off, 64);
    __shared__ float s_red[4];
    int lane = threadIdx.x & 63, wid = threadIdx.x >> 6;
    if (lane == 0) s_red[wid] = v;
    __syncthreads();
    if (threadIdx.x == 0) atomicAdd(dst, s_red[0] + s_red[1] + s_red[2] + s_red[3]);
}

// ---------------------------------------------------------------
// Adjoint At: LDS-staged table, 32-column x-half of one y-row per block.
// Block = 512 threads = 32 cols x 8 slices x 2 tap-halves.
// blockIdx: Yb = b>>4, xhalf = (b>>3)&1, split = b&7.
// grid = 64*2*8 = 1024 blocks -> 4 blocks/CU = 32 waves/CU.
// Writes partial volume per split (disjoint voxels per block).
// ---------------------------------------------------------------
__global__ __launch_bounds__(512, 8) void k_atv(const float* __restrict__ g,
                                                float* __restrict__ part,
                                                const float* __restrict__ tab) {
    __shared__ float stab[8 * 27 * 16];     // 13.8 KB
    __shared__ float cols[32][COL_PAD];     // 8.6 KB

    int tid = threadIdx.x;
    int Yb    = blockIdx.x >> 4;
    int xhalf = (blockIdx.x >> 3) & 1;
    int split = blockIdx.x & 7;

    // stage 8-slice table slab (coalesced float4): 864 float4
    {
        const float4* src = (const float4*)(tab + split * 8 * 27 * 16);
        float4* dst = (float4*)stab;
#pragma unroll
        for (int i = 0; i < 2; ++i) {
            int j = tid + i * 512;
            if (j < 864) dst[j] = src[j];
        }
    }
    // zero accumulators: 32*67 = 2144 floats = 536 float4
    {
        float4* c4 = (float4*)&cols[0][0];
#pragma unroll
        for (int i = 0; i < 2; ++i) {
            int j = tid + i * 512;
            if (j < 536) c4[j] = make_float4(0.f, 0.f, 0.f, 0.f);
        }
    }
    __syncthreads();

    int xl   = tid & 31;               // column within x-half
    int half = (tid >> 5) & 1;         // tap half
    int sg   = tid >> 6;               // slice group 0..7
    int s    = split * 8 + sg;
    float X = (float)(xhalf * 32 + xl);
    float Y = (float)Yb;

    const float* tb = stab + sg * 27 * 16;
    int gbase = s << 12;

    // window base from center tap (k=13)
    const float* ec = tb + 13 * 16;
    float4 c0 = *(const float4*)(ec);
    float4 c1 = *(const float4*)(ec + 4);
    float4 c2 = *(const float4*)(ec + 8);
    float4 c3 = *(const float4*)(ec + 12);
    float rxc = X - c2.z, ryc = Y - c2.w;
    float wsc = c0.x * rxc + c0.y * ryc;
    float hsc = c0.z * rxc + c0.w * ryc;
    float pzc = fmaf(wsc, c1.z, fmaf(hsc, c2.y, c3.x));
    float basef = floorf(pzc) - 2.f;
    int   basei = (int)basef;

    float acc[WIN];
#pragma unroll
    for (int j = 0; j < WIN; ++j) acc[j] = 0.f;

    int kbeg = half * 14;
    int kend = kbeg + 14 - half;       // half0: 0..13 (14), half1: 14..26 (13)
    for (int k = kbeg; k < kend; ++k) {
        const float* e = tb + k * 16;
        float4 e0 = *(const float4*)(e);
        float4 e1 = *(const float4*)(e + 4);
        float4 e2 = *(const float4*)(e + 8);
        float4 e3 = *(const float4*)(e + 12);
        float Ux = e1.x, Uy = e1.y, Uz = e1.z, Vx = e1.w;
        float Vy = e2.x, Vz = e2.y;
        float Cxr = e2.z - X, Cyr = e2.w - Y;   // C - voxel(x,y)
        float psfk = e3.y;
        float ws = e0.x * (-Cxr) + e0.y * (-Cyr);
        float hs = e0.z * (-Cxr) + e0.w * (-Cyr);
        float w0f = floorf(ws), h0f = floorf(hs);
        int w0 = (int)w0f, h0 = (int)h0f;
#pragma unroll
        for (int dh = 0; dh < 2; ++dh) {
            float fh = h0f + (float)dh;
            int hi = h0 + dh;
            int hok = ((unsigned)hi < 64u) ? 1 : 0;
            int hc = min(max(hi, 0), 63);
            float tx = fmaf(fh, Vx, Cxr);
            float ty = fmaf(fh, Vy, Cyr);
            float tz = fmaf(fh, Vz, e3.x);
#pragma unroll
            for (int dw = 0; dw < 2; ++dw) {
                float fw = w0f + (float)dw;
                int wi = w0 + dw;
                int ok = ((unsigned)wi < 64u) ? hok : 0;
                int wc = min(max(wi, 0), 63);
                float ddx = fmaf(fw, Ux, tx);          // px - X
                float ddy = fmaf(fw, Uy, ty);          // py - Y
                float wx = fmaxf(0.f, 1.f - fabsf(ddx));
                float wy = fmaxf(0.f, 1.f - fabsf(ddy));
                float gv = g[gbase + (hc << 6) + wc];
                float val = ok ? (wx * wy * psfk * gv) : 0.f;
                float prel = fmaf(fw, Uz, tz) - basef; // pz - base
#pragma unroll
                for (int j = 0; j < WIN; ++j) {
                    float t = fmaxf(0.f, 1.f - fabsf(prel - (float)j));
                    acc[j] = fmaf(val, t, acc[j]);
                }
            }
        }
    }

#pragma unroll
    for (int j = 0; j < WIN; ++j) {
        int zj = basei + j;
        int okz = ((unsigned)zj < 64u);
        int zc = min(max(zj, 0), 63);
        atomicAdd(&cols[xl][zc], okz ? acc[j] : 0.f);
    }
    __syncthreads();

    // write partial: 2048 voxels (32 cols x 64 z)
    float* pout = part + split * NVOX + (Yb << 6) + xhalf * 32;
#pragma unroll
    for (int i = 0; i < 4; ++i) {
        int j = tid + i * 512;           // j < 2048
        int z = j >> 5, x = j & 31;
        pout[(z << 12) + x] = cols[x][z];
    }
}

// ---------------- partial-sum consumers & CG updates ----------------

__device__ __forceinline__ float sum8(const float* __restrict__ part, int i) {
    float a = 0.f;
#pragma unroll
    for (int j = 0; j < SPLIT; ++j) a += part[j * NVOX + i];
    return a;
}

// r = p = sum8(part); scal[0] += r.r      (part holds At(slices - A(x0)))
__global__ __launch_bounds__(256) void k_residual8(const float* __restrict__ part,
                                                   float* __restrict__ r,
                                                   float* __restrict__ p,
                                                   float* __restrict__ scal) {
    int i = blockIdx.x * 256 + threadIdx.x;
    float rv = sum8(part, i);
    r[i] = rv;
    p[i] = rv;
    block_reduce_atomic(rv * rv, &scal[0]);
}

// Ap = sum8(part); dst += p.Ap
__global__ __launch_bounds__(256) void k_dot_reduce8(const float* __restrict__ part,
                                                     const float* __restrict__ p,
                                                     float* __restrict__ Ap,
                                                     float* __restrict__ dst) {
    int i = blockIdx.x * 256 + threadIdx.x;
    float apv = sum8(part, i);
    Ap[i] = apv;
    block_reduce_atomic(p[i] * apv, dst);
}

// dst += p . sum8(part)
__global__ __launch_bounds__(256) void k_dot8(const float* __restrict__ part,
                                              const float* __restrict__ p,
                                              float* __restrict__ dst) {
    int i = blockIdx.x * 256 + threadIdx.x;
    block_reduce_atomic(p[i] * sum8(part, i), dst);
}

// alpha = scal[0]/scal[1]; x_out = x_in + alpha p; r -= alpha Ap; scal[2] += r.r
__global__ __launch_bounds__(256) void k_update_xr(const float* __restrict__ x_in,
                                                   float* __restrict__ x_out,
                                                   float* __restrict__ r,
                                                   const float* __restrict__ p,
                                                   const float* __restrict__ Ap,
                                                   float* __restrict__ scal) {
    int i = blockIdx.x * 256 + threadIdx.x;
    float alpha = scal[0] / scal[1];
    x_out[i] = fmaf(alpha, p[i], x_in[i]);
    float rv = fmaf(-alpha, Ap[i], r[i]);
    r[i] = rv;
    block_reduce_atomic(rv * rv, &scal[2]);
}

__global__ __launch_bounds__(256) void k_update_p(float* __restrict__ p,
                                                  const float* __restrict__ r,
                                                  const float* __restrict__ scal) {
    int i = blockIdx.x * 256 + threadIdx.x;
    float beta = scal[2] / scal[0];
    p[i] = fmaf(beta, p[i], r[i]);
}

__global__ __launch_bounds__(256) void k_final(const float* __restrict__ x,
                                               const float* __restrict__ p,
                                               const float* __restrict__ scal,
                                               float* __restrict__ out) {
    int i = blockIdx.x * 256 + threadIdx.x;
    float alpha = scal[2] / scal[3];
    float v = fmaf(alpha, p[i], x[i]);
    out[i] = v > 0.f ? v : 0.f;
}

extern "C" void kernel_launch(void* const* d_in, const int* in_sizes, int n_in,
                              void* d_out, int out_size, void* d_ws, size_t ws_size,
                              hipStream_t stream) {
    const float* transforms = (const float*)d_in[0];
    const float* slices     = (const float*)d_in[1];
    const float* volume     = (const float*)d_in[2];
    const float* psf        = (const float*)d_in[3];
    float* out = (float*)d_out;

    float* tab    = (float*)d_ws;             // 1728*16 floats (0.11 MB)
    float* part   = tab    + NTAB * 16;       // 8 * NVOX (8 MB)
    float* vol_x  = part   + SPLIT * NVOX;
    float* vol_r  = vol_x  + NVOX;
    float* vol_p  = vol_r  + NVOX;
    float* gbuf   = vol_p  + NVOX;            // doubles as Ap (dead/live disjoint)
    float* scal   = gbuf   + NPIX;            // 4 floats: rr0, pAp0, rr1, pAp1
    float* Ap     = gbuf;

    const int ablk = 64 * 2 * SPLIT;          // 1024 (k_atv)
    const int fblk = NPIX * 4 / 256;          // 4096 (k_a: 4 lanes/pixel)
    const int vblk = NVOX / 256;              // 16

    hipMemsetAsync(scal, 0, 4 * sizeof(float), stream);

    k_setup<<<(NTAB + 255) / 256, 256, 0, stream>>>(transforms, psf, tab);

    // r0 = At(slices - A(x0)); p = r0; rr0
    k_a<true><<<fblk, 256, 0, stream>>>(volume, gbuf, transforms, psf, slices);
    k_atv<<<ablk, 512, 0, stream>>>(gbuf, part, tab);
    k_residual8<<<vblk, 256, 0, stream>>>(part, vol_r, vol_p, scal);

    // iter 0: Ap = AtA(p); alpha; x,r updates; beta; p update
    k_a<false><<<fblk, 256, 0, stream>>>(vol_p, gbuf, transforms, psf, nullptr);
    k_atv<<<ablk, 512, 0, stream>>>(gbuf, part, tab);
    k_dot_reduce8<<<vblk, 256, 0, stream>>>(part, vol_p, Ap, &scal[1]);
    k_update_xr<<<vblk, 256, 0, stream>>>(volume, vol_x, vol_r, vol_p, Ap, scal);
    k_update_p<<<vblk, 256, 0, stream>>>(vol_p, vol_r, scal);

    // iter 1: pAp1; out = relu(x + alpha p)
    k_a<false><<<fblk, 256, 0, stream>>>(vol_p, gbuf, transforms, psf, nullptr);
    k_atv<<<ablk, 512, 0, stream>>>(gbuf, part, tab);
    k_dot8<<<vblk, 256, 0, stream>>>(part, vol_p, &scal[3]);
    k_final<<<vblk, 256, 0, stream>>>(vol_x, vol_p, scal, out);
}

// Round 9
// 289.914 us; speedup vs baseline: 1.4762x; 1.0278x over previous
//
#include <hip/hip_runtime.h>

typedef __attribute__((ext_vector_type(2))) float f32x2;

#define NS 64
#define HH 64
#define WW 64
#define VD 64
#define VH 64
#define VW 64
#define NVOX (VD*VH*VW)
#define NPIX (NS*HH*WW)
#define RES 1.5f
#define NTAB (NS*27)
#define WIN 6
#define SPLIT 4
#define COL_PAD 67
#define GP_ROW 68
#define GP_SLC (66*GP_ROW)      // 4488 floats per padded slice
#define GP_TOT (NS*GP_SLC)      // 287232

// ---------------------------------------------------------------
// Per-(slice,tap) affine table:  pos = w*U + h*V + C
// entry layout (16 floats), packed-math-friendly:
//  [0..3]  a,c,b,d    (inverse of [[Ux,Vx],[Uy,Vy]]: ws=a*rx+b*ry, hs=c*rx+d*ry)
//  [4..7]  Ux,Uy,Vx,Vy
//  [8..11] Uz,Vz,Cx,Cy
//  [12..15]Cz,psf_k,0,0
// ---------------------------------------------------------------
__global__ __launch_bounds__(256) void k_setup(const float* __restrict__ tr,
                                               const float* __restrict__ psf,
                                               float* __restrict__ tab) {
    int i = blockIdx.x * 256 + threadIdx.x;
    if (i >= NTAB) return;
    int s = i / 27, k = i % 27;
    const float* p = tr + s * 12;
    float R00 = p[0], R01 = p[1], R02 = p[2],  t0 = p[3];
    float R10 = p[4], R11 = p[5], R12 = p[6],  t1 = p[7];
    float R20 = p[8], R21 = p[9], R22 = p[10], t2 = p[11];
    float Ux = RES * R00, Uy = RES * R10, Uz = RES * R20;
    float Vx = RES * R01, Vy = RES * R11, Vz = RES * R21;
    float ox = (float)(k % 3 - 1), oy = (float)((k / 3) % 3 - 1), oz = (float)(k / 9 - 1);
    float Cx = t0 + 31.5f + R00 * ox + R01 * oy + R02 * oz - 31.5f * (Ux + Vx);
    float Cy = t1 + 31.5f + R10 * ox + R11 * oy + R12 * oz - 31.5f * (Uy + Vy);
    float Cz = t2 + 31.5f + R20 * ox + R21 * oy + R22 * oz - 31.5f * (Uz + Vz);
    float inv = 1.f / (Ux * Vy - Uy * Vx);
    float* e = tab + i * 16;
    e[0] = Vy * inv;  e[1] = -Uy * inv;  e[2] = -Vx * inv; e[3] = Ux * inv;
    e[4] = Ux; e[5] = Uy; e[6] = Vx; e[7] = Vy;
    e[8] = Uz; e[9] = Vz; e[10] = Cx; e[11] = Cy;
    e[12] = Cz; e[13] = psf[k]; e[14] = 0.f; e[15] = 0.f;
}

// ---------------------------------------------------------------
// Branch-free trilinear gather (clamped idx, zeroed weights) — k_a only.
// ---------------------------------------------------------------
__device__ __forceinline__ float trilin_gather_bf(const float* __restrict__ vol,
                                                  float px, float py, float pz) {
    float x0 = floorf(px), y0 = floorf(py), z0 = floorf(pz);
    float fx = px - x0, fy = py - y0, fz = pz - z0;
    int ix = (int)x0, iy = (int)y0, iz = (int)z0;

    float wx0 = ((unsigned)ix       < 64u) ? (1.f - fx) : 0.f;
    float wx1 = ((unsigned)(ix + 1) < 64u) ? fx         : 0.f;
    float wy0 = ((unsigned)iy       < 64u) ? (1.f - fy) : 0.f;
    float wy1 = ((unsigned)(iy + 1) < 64u) ? fy         : 0.f;
    float wz0 = ((unsigned)iz       < 64u) ? (1.f - fz) : 0.f;
    float wz1 = ((unsigned)(iz + 1) < 64u) ? fz         : 0.f;

    int xc0 = min(max(ix, 0), 63),     xc1 = min(max(ix + 1, 0), 63);
    int yc0 = min(max(iy, 0), 63) << 6,  yc1 = min(max(iy + 1, 0), 63) << 6;
    int zc0 = min(max(iz, 0), 63) << 12, zc1 = min(max(iz + 1, 0), 63) << 12;

    float v000 = vol[zc0 + yc0 + xc0], v001 = vol[zc0 + yc0 + xc1];
    float v010 = vol[zc0 + yc1 + xc0], v011 = vol[zc0 + yc1 + xc1];
    float v100 = vol[zc1 + yc0 + xc0], v101 = vol[zc1 + yc0 + xc1];
    float v110 = vol[zc1 + yc1 + xc0], v111 = vol[zc1 + yc1 + xc1];

    float w00 = wx0 * wy0, w01 = wx1 * wy0, w10 = wx0 * wy1, w11 = wx1 * wy1;
    float lo = fmaf(w00, v000, fmaf(w01, v001, fmaf(w10, v010, w11 * v011)));
    float hi = fmaf(w00, v100, fmaf(w01, v101, fmaf(w10, v110, w11 * v111)));
    return fmaf(wz0, lo, wz1 * hi);
}

// ---------------------------------------------------------------
// Forward projection A: 4 lanes per pixel, taps k = q + 4*j.
// Output into ZERO-PADDED g (66 rows x 68 cols per slice).
// SUB: g = slc - A(vin)
// ---------------------------------------------------------------
template<bool SUB>
__global__ __launch_bounds__(256) void k_a(const float* __restrict__ vin,
                                           float* __restrict__ gp,
                                           const float* __restrict__ tr,
                                           const float* __restrict__ psf,
                                           const float* __restrict__ slc) {
    __shared__ float s_psf[27];
    if (threadIdx.x < 27) s_psf[threadIdx.x] = psf[threadIdx.x];
    __syncthreads();
    int gid = blockIdx.x * 256 + threadIdx.x;
    int pixel = gid >> 2, q = gid & 3;
    int s = pixel >> 12;
    int pix = pixel & 4095;
    int h = pix >> 6, w = pix & 63;
    const float* p = tr + s * 12;
    float R0 = p[0], R1 = p[1], R2 = p[2],  t0 = p[3];
    float R3 = p[4], R4 = p[5], R5 = p[6],  t1 = p[7];
    float R6 = p[8], R7 = p[9], R8 = p[10], t2 = p[11];
    float xs = ((float)w - 31.5f) * RES;
    float ys = ((float)h - 31.5f) * RES;
    float p0x = fmaf(R0, xs, fmaf(R1, ys, t0)) + 31.5f;
    float p0y = fmaf(R3, xs, fmaf(R4, ys, t1)) + 31.5f;
    float p0z = fmaf(R6, xs, fmaf(R7, ys, t2)) + 31.5f;
    float a = 0.f;
#pragma unroll
    for (int j = 0; j < 7; ++j) {
        int k = q + 4 * j;
        if (k < 27) {
            float ox = (float)(k % 3 - 1), oy = (float)((k / 3) % 3 - 1), oz = (float)(k / 9 - 1);
            float px = p0x + ox * R0 + oy * R1 + oz * R2;
            float py = p0y + ox * R3 + oy * R4 + oz * R5;
            float pz = p0z + ox * R6 + oy * R7 + oz * R8;
            a = fmaf(s_psf[k], trilin_gather_bf(vin, px, py, pz), a);
        }
    }
    a += __shfl_xor(a, 1);
    a += __shfl_xor(a, 2);
    if (q == 0) gp[s * GP_SLC + (h + 1) * GP_ROW + (w + 1)] = SUB ? (slc[pixel] - a) : a;
}

// ---------------- block reduce -> one atomic (256-thr kernels) ----------------
__device__ __forceinline__ void block_reduce_atomic(float v, float* dst) {
#pragma unroll
    for (int off = 32; off > 0; off >>= 1) v += __shfl_down(v, off, 64);
    __shared__ float s_red[4];
    int lane = threadIdx.x & 63, wid = threadIdx.x >> 6;
    if (lane == 0) s_red[wid] = v;
    __syncthreads();
    if (threadIdx.x == 0) atomicAdd(dst, s_red[0] + s_red[1] + s_red[2] + s_red[3]);
}

// ---------------------------------------------------------------
// Adjoint At: LDS-staged table, 32-col x-half of one y-row per block.
// Block = 512 thr = 32 cols x 16 slices. grid = 64*2*4 = 512.
// Padded-g reads (no bounds logic): med3-clamped corner base + auto-zero
// weights. 6-slot z-window in PACKED fp32 (3x f32x2).
// Writes partial volume per split (4 partials).
// ---------------------------------------------------------------
__global__ __launch_bounds__(512, 4) void k_atv(const float* __restrict__ g,
                                                float* __restrict__ part,
                                                const float* __restrict__ tab) {
    __shared__ float stab[16 * 27 * 16];    // 27.6 KB
    __shared__ float cols[32][COL_PAD];     // 8.6 KB

    int tid = threadIdx.x;
    int Yb    = blockIdx.x >> 3;
    int xhalf = (blockIdx.x >> 2) & 1;
    int split = blockIdx.x & 3;

    // stage 16-slice table slab: 1728 float4
    {
        const float4* src = (const float4*)(tab + split * 16 * 27 * 16);
        float4* dst = (float4*)stab;
#pragma unroll
        for (int i = 0; i < 4; ++i) {
            int j = tid + i * 512;
            if (j < 1728) dst[j] = src[j];
        }
    }
    // zero accumulators: 32*67 = 2144 floats = 536 float4
    {
        float4* c4 = (float4*)&cols[0][0];
#pragma unroll
        for (int i = 0; i < 2; ++i) {
            int j = tid + i * 512;
            if (j < 536) c4[j] = make_float4(0.f, 0.f, 0.f, 0.f);
        }
    }
    __syncthreads();

    int xl = tid & 31;
    int sg = tid >> 5;                  // 0..15
    int s  = split * 16 + sg;
    float X = (float)(xhalf * 32 + xl);
    float Y = (float)Yb;

    const float* tb = stab + sg * 27 * 16;
    int gbase = s * GP_SLC;

    // window base from center tap (k=13)
    {
    }
    const float* ec = tb + 13 * 16;
    float4 ce0 = *(const float4*)(ec);
    float4 ce2 = *(const float4*)(ec + 8);
    float4 ce3 = *(const float4*)(ec + 12);
    float rxc = X - ce2.z, ryc = Y - ce2.w;
    float wsc = ce0.x * rxc + ce0.z * ryc;
    float hsc = ce0.y * rxc + ce0.w * ryc;
    float pzc = fmaf(wsc, ce2.x, fmaf(hsc, ce2.y, ce3.x));
    float basef = floorf(pzc) - 2.f;
    int   basei = (int)basef;

    f32x2 a01 = {0.f, 0.f}, a23 = {0.f, 0.f}, a45 = {0.f, 0.f};
    const f32x2 zero2 = {0.f, 0.f};
    const f32x2 cA0 = {1.f, 2.f}, cB0 = {-1.f, 0.f};
    const f32x2 cA1 = {3.f, 4.f}, cB1 = {1.f, 2.f};
    const f32x2 cA2 = {5.f, 6.f}, cB2 = {3.f, 4.f};

#pragma unroll 3
    for (int k = 0; k < 27; ++k) {
        const float* e = tb + k * 16;
        float4 e0 = *(const float4*)(e);
        float4 e1 = *(const float4*)(e + 4);
        float4 e2 = *(const float4*)(e + 8);
        float4 e3 = *(const float4*)(e + 12);
        float rx = X - e2.z, ry = Y - e2.w;        // X - Cx, Y - Cy
        float ws = e0.x * rx + e0.z * ry;          // a*rx + b*ry
        float hs = e0.y * rx + e0.w * ry;          // c*rx + d*ry
        float w0f = __builtin_amdgcn_fmed3f(floorf(ws), -1.f, 63.f);
        float h0f = __builtin_amdgcn_fmed3f(floorf(hs), -1.f, 63.f);
        int wA = (int)w0f, hA = (int)h0f;
        float Ux = e1.x, Uy = e1.y, Vx = e1.z, Vy = e1.w;
        float Uz = e2.x, Vz = e2.y;
        float Czb = e3.x - basef;
        float psfk = e3.y;
        float Cxr = -rx, Cyr = -ry;                // C - voxel(x,y)
        int colbase = gbase + wA + 1;
#pragma unroll
        for (int dh = 0; dh < 2; ++dh) {
            float fh = h0f + (float)dh;
            float tx  = fmaf(fh, Vx, Cxr);
            float ty  = fmaf(fh, Vy, Cyr);
            float tzb = fmaf(fh, Vz, Czb);
            int rowoff = colbase + (hA + 1 + dh) * GP_ROW;
#pragma unroll
            for (int dw = 0; dw < 2; ++dw) {
                float fw = w0f + (float)dw;
                float ddx = fmaf(fw, Ux, tx);      // px - X
                float ddy = fmaf(fw, Uy, ty);      // py - Y
                float wx = fmaxf(1.f - fabsf(ddx), 0.f);
                float wy = fmaxf(1.f - fabsf(ddy), 0.f);
                float gv = g[rowoff + dw];         // padded: OOB -> 0
                float val = wx * wy * psfk * gv;
                float prel = fmaf(fw, Uz, tzb);    // pz - basef
                f32x2 v2 = {val, val};
                f32x2 p2 = {prel, prel};
                // tent: max(0, min((1+j)-prel, prel-(j-1))) for slot pairs
                a01 += v2 * __builtin_elementwise_max(zero2,
                          __builtin_elementwise_min(cA0 - p2, p2 - cB0));
                a23 += v2 * __builtin_elementwise_max(zero2,
                          __builtin_elementwise_min(cA1 - p2, p2 - cB1));
                a45 += v2 * __builtin_elementwise_max(zero2,
                          __builtin_elementwise_min(cA2 - p2, p2 - cB2));
            }
        }
    }

    float accs[WIN] = {a01.x, a01.y, a23.x, a23.y, a45.x, a45.y};
#pragma unroll
    for (int j = 0; j < WIN; ++j) {
        int zj = basei + j;
        int okz = ((unsigned)zj < 64u);
        int zc = min(max(zj, 0), 63);
        atomicAdd(&cols[xl][zc], okz ? accs[j] : 0.f);
    }
    __syncthreads();

    // write partial: 2048 voxels (32 cols x 64 z)
    float* pout = part + split * NVOX + (Yb << 6) + xhalf * 32;
#pragma unroll
    for (int i = 0; i < 4; ++i) {
        int j = tid + i * 512;
        int z = j >> 5, x = j & 31;
        pout[(z << 12) + x] = cols[x][z];
    }
}

// ---------------- partial-sum consumers & CG updates ----------------

__device__ __forceinline__ float sum4p(const float* __restrict__ part, int i) {
    return (part[i] + part[NVOX + i]) + (part[2 * NVOX + i] + part[3 * NVOX + i]);
}

// r = p = sum4(part); scal[0] += r.r
__global__ __launch_bounds__(256) void k_residual4(const float* __restrict__ part,
                                                   float* __restrict__ r,
                                                   float* __restrict__ p,
                                                   float* __restrict__ scal) {
    int i = blockIdx.x * 256 + threadIdx.x;
    float rv = sum4p(part, i);
    r[i] = rv;
    p[i] = rv;
    block_reduce_atomic(rv * rv, &scal[0]);
}

// Ap = sum4(part); dst += p.Ap
__global__ __launch_bounds__(256) void k_dot_reduce4(const float* __restrict__ part,
                                                     const float* __restrict__ p,
                                                     float* __restrict__ Ap,
                                                     float* __restrict__ dst) {
    int i = blockIdx.x * 256 + threadIdx.x;
    float apv = sum4p(part, i);
    Ap[i] = apv;
    block_reduce_atomic(p[i] * apv, dst);
}

// dst += p . sum4(part)
__global__ __launch_bounds__(256) void k_dot4(const float* __restrict__ part,
                                              const float* __restrict__ p,
                                              float* __restrict__ dst) {
    int i = blockIdx.x * 256 + threadIdx.x;
    block_reduce_atomic(p[i] * sum4p(part, i), dst);
}

// alpha = scal[0]/scal[1]; x_out = x_in + alpha p; r -= alpha Ap; scal[2] += r.r
__global__ __launch_bounds__(256) void k_update_xr(const float* __restrict__ x_in,
                                                   float* __restrict__ x_out,
                                                   float* __restrict__ r,
                                                   const float* __restrict__ p,
                                                   const float* __restrict__ Ap,
                                                   float* __restrict__ scal) {
    int i = blockIdx.x * 256 + threadIdx.x;
    float alpha = scal[0] / scal[1];
    x_out[i] = fmaf(alpha, p[i], x_in[i]);
    float rv = fmaf(-alpha, Ap[i], r[i]);
    r[i] = rv;
    block_reduce_atomic(rv * rv, &scal[2]);
}

__global__ __launch_bounds__(256) void k_update_p(float* __restrict__ p,
                                                  const float* __restrict__ r,
                                                  const float* __restrict__ scal) {
    int i = blockIdx.x * 256 + threadIdx.x;
    float beta = scal[2] / scal[0];
    p[i] = fmaf(beta, p[i], r[i]);
}

__global__ __launch_bounds__(256) void k_final(const float* __restrict__ x,
                                               const float* __restrict__ p,
                                               const float* __restrict__ scal,
                                               float* __restrict__ out) {
    int i = blockIdx.x * 256 + threadIdx.x;
    float alpha = scal[2] / scal[3];
    float v = fmaf(alpha, p[i], x[i]);
    out[i] = v > 0.f ? v : 0.f;
}

extern "C" void kernel_launch(void* const* d_in, const int* in_sizes, int n_in,
                              void* d_out, int out_size, void* d_ws, size_t ws_size,
                              hipStream_t stream) {
    const float* transforms = (const float*)d_in[0];
    const float* slices     = (const float*)d_in[1];
    const float* volume     = (const float*)d_in[2];
    const float* psf        = (const float*)d_in[3];
    float* out = (float*)d_out;

    // layout: tab | gbuf(padded) | scal | part(4) | x | r | p | Ap   (~9.7 MB)
    float* tab    = (float*)d_ws;             // NTAB*16 = 27648
    float* gbuf   = tab    + NTAB * 16;       // GP_TOT = 287232 (zero-padded g)
    float* scal   = gbuf   + GP_TOT;          // 4 floats (+ pad to 8)
    float* part   = scal   + 8;               // 4 * NVOX
    float* vol_x  = part   + SPLIT * NVOX;
    float* vol_r  = vol_x  + NVOX;
    float* vol_p  = vol_r  + NVOX;
    float* Ap     = vol_p  + NVOX;

    const int ablk = 64 * 2 * SPLIT;          // 512 (k_atv)
    const int fblk = NPIX * 4 / 256;          // 4096 (k_a)
    const int vblk = NVOX / 256;              // 16

    // one memset covers padded-g borders AND scal
    hipMemsetAsync(gbuf, 0, (GP_TOT + 8) * sizeof(float), stream);

    k_setup<<<(NTAB + 255) / 256, 256, 0, stream>>>(transforms, psf, tab);

    // r0 = At(slices - A(x0)); p = r0; rr0
    k_a<true><<<fblk, 256, 0, stream>>>(volume, gbuf, transforms, psf, slices);
    k_atv<<<ablk, 512, 0, stream>>>(gbuf, part, tab);
    k_residual4<<<vblk, 256, 0, stream>>>(part, vol_r, vol_p, scal);

    // iter 0: Ap = AtA(p); alpha; x,r updates; beta; p update
    k_a<false><<<fblk, 256, 0, stream>>>(vol_p, gbuf, transforms, psf, nullptr);
    k_atv<<<ablk, 512, 0, stream>>>(gbuf, part, tab);
    k_dot_reduce4<<<vblk, 256, 0, stream>>>(part, vol_p, Ap, &scal[1]);
    k_update_xr<<<vblk, 256, 0, stream>>>(volume, vol_x, vol_r, vol_p, Ap, scal);
    k_update_p<<<vblk, 256, 0, stream>>>(vol_p, vol_r, scal);

    // iter 1: pAp1; out = relu(x + alpha p)
    k_a<false><<<fblk, 256, 0, stream>>>(vol_p, gbuf, transforms, psf, nullptr);
    k_atv<<<ablk, 512, 0, stream>>>(gbuf, part, tab);
    k_dot4<<<vblk, 256, 0, stream>>>(part, vol_p, &scal[3]);
    k_final<<<vblk, 256, 0, stream>>>(vol_x, vol_p, scal, out);
}

// Round 10
// 273.110 us; speedup vs baseline: 1.5671x; 1.0615x over previous
//
#include <hip/hip_runtime.h>

#define NS 64
#define HH 64
#define WW 64
#define VD 64
#define VH 64
#define VW 64
#define NVOX (VD*VH*VW)
#define NPIX (NS*HH*WW)
#define RES 1.5f
#define NTAB (NS*27)
#define WIN 6
#define SPLIT 8
#define COL_PAD 67
#define GP_ROW 68
#define GP_SLC (66*GP_ROW)      // 4488 floats per padded slice
#define GP_TOT (NS*GP_SLC)      // 287232

// ---------------------------------------------------------------
// Per-(slice,tap) affine table:  pos = w*U + h*V + C
// entry layout (16 floats):
//  [0..3]  a,c,b,d    (ws = a*rx + b*ry, hs = c*rx + d*ry)
//  [4..7]  Ux,Uy,Vx,Vy
//  [8..11] Uz,Vz,Cx,Cy
//  [12..15]Cz,psf_k,0,0
// ---------------------------------------------------------------
__global__ __launch_bounds__(256) void k_setup(const float* __restrict__ tr,
                                               const float* __restrict__ psf,
                                               float* __restrict__ tab) {
    int i = blockIdx.x * 256 + threadIdx.x;
    if (i >= NTAB) return;
    int s = i / 27, k = i % 27;
    const float* p = tr + s * 12;
    float R00 = p[0], R01 = p[1], R02 = p[2],  t0 = p[3];
    float R10 = p[4], R11 = p[5], R12 = p[6],  t1 = p[7];
    float R20 = p[8], R21 = p[9], R22 = p[10], t2 = p[11];
    float Ux = RES * R00, Uy = RES * R10, Uz = RES * R20;
    float Vx = RES * R01, Vy = RES * R11, Vz = RES * R21;
    float ox = (float)(k % 3 - 1), oy = (float)((k / 3) % 3 - 1), oz = (float)(k / 9 - 1);
    float Cx = t0 + 31.5f + R00 * ox + R01 * oy + R02 * oz - 31.5f * (Ux + Vx);
    float Cy = t1 + 31.5f + R10 * ox + R11 * oy + R12 * oz - 31.5f * (Uy + Vy);
    float Cz = t2 + 31.5f + R20 * ox + R21 * oy + R22 * oz - 31.5f * (Uz + Vz);
    float inv = 1.f / (Ux * Vy - Uy * Vx);
    float* e = tab + i * 16;
    e[0] = Vy * inv;  e[1] = -Uy * inv;  e[2] = -Vx * inv; e[3] = Ux * inv;
    e[4] = Ux; e[5] = Uy; e[6] = Vx; e[7] = Vy;
    e[8] = Uz; e[9] = Vz; e[10] = Cx; e[11] = Cy;
    e[12] = Cz; e[13] = psf[k]; e[14] = 0.f; e[15] = 0.f;
}

// ---------------------------------------------------------------
// Branch-free trilinear gather (clamped idx, zeroed weights).
// Caller guarantees at least partial overlap (per-tap skip outside).
// ---------------------------------------------------------------
__device__ __forceinline__ float trilin_gather_bf(const float* __restrict__ vol,
                                                  float px, float py, float pz) {
    float x0 = floorf(px), y0 = floorf(py), z0 = floorf(pz);
    float fx = px - x0, fy = py - y0, fz = pz - z0;
    int ix = (int)x0, iy = (int)y0, iz = (int)z0;

    float wx0 = ((unsigned)ix       < 64u) ? (1.f - fx) : 0.f;
    float wx1 = ((unsigned)(ix + 1) < 64u) ? fx         : 0.f;
    float wy0 = ((unsigned)iy       < 64u) ? (1.f - fy) : 0.f;
    float wy1 = ((unsigned)(iy + 1) < 64u) ? fy         : 0.f;
    float wz0 = ((unsigned)iz       < 64u) ? (1.f - fz) : 0.f;
    float wz1 = ((unsigned)(iz + 1) < 64u) ? fz         : 0.f;

    int xc0 = min(max(ix, 0), 63),     xc1 = min(max(ix + 1, 0), 63);
    int yc0 = min(max(iy, 0), 63) << 6,  yc1 = min(max(iy + 1, 0), 63) << 6;
    int zc0 = min(max(iz, 0), 63) << 12, zc1 = min(max(iz + 1, 0), 63) << 12;

    float v000 = vol[zc0 + yc0 + xc0], v001 = vol[zc0 + yc0 + xc1];
    float v010 = vol[zc0 + yc1 + xc0], v011 = vol[zc0 + yc1 + xc1];
    float v100 = vol[zc1 + yc0 + xc0], v101 = vol[zc1 + yc0 + xc1];
    float v110 = vol[zc1 + yc1 + xc0], v111 = vol[zc1 + yc1 + xc1];

    float w00 = wx0 * wy0, w01 = wx1 * wy0, w10 = wx0 * wy1, w11 = wx1 * wy1;
    float lo = fmaf(w00, v000, fmaf(w01, v001, fmaf(w10, v010, w11 * v011)));
    float hi = fmaf(w00, v100, fmaf(w01, v101, fmaf(w10, v110, w11 * v111)));
    return fmaf(wz0, lo, wz1 * hi);
}

// ---------------------------------------------------------------
// Forward projection A: 1 thread per pixel, 27 taps with per-tap
// OOB skip (no loads, no weight math for fully-outside taps).
// Output into ZERO-PADDED g. SUB: g = slc - A(vin).
// ---------------------------------------------------------------
template<bool SUB>
__global__ __launch_bounds__(256) void k_a(const float* __restrict__ vin,
                                           float* __restrict__ gp,
                                           const float* __restrict__ tr,
                                           const float* __restrict__ psf,
                                           const float* __restrict__ slc) {
    __shared__ float s_psf[27];
    if (threadIdx.x < 27) s_psf[threadIdx.x] = psf[threadIdx.x];
    __syncthreads();
    int gid = blockIdx.x * 256 + threadIdx.x;   // pixel id
    int s = gid >> 12;
    int h = (gid >> 6) & 63, w = gid & 63;
    const float* p = tr + s * 12;
    float R0 = p[0], R1 = p[1], R2 = p[2],  t0 = p[3];
    float R3 = p[4], R4 = p[5], R5 = p[6],  t1 = p[7];
    float R6 = p[8], R7 = p[9], R8 = p[10], t2 = p[11];
    float xs = ((float)w - 31.5f) * RES;
    float ys = ((float)h - 31.5f) * RES;
    float p0x = fmaf(R0, xs, fmaf(R1, ys, t0)) + 31.5f;
    float p0y = fmaf(R3, xs, fmaf(R4, ys, t1)) + 31.5f;
    float p0z = fmaf(R6, xs, fmaf(R7, ys, t2)) + 31.5f;
    float a = 0.f;
#pragma unroll
    for (int k = 0; k < 27; ++k) {
        const float ox = (float)(k % 3 - 1), oy = (float)((k / 3) % 3 - 1), oz = (float)(k / 9 - 1);
        float px = p0x + ox * R0 + oy * R1 + oz * R2;
        float py = p0y + ox * R3 + oy * R4 + oz * R5;
        float pz = p0z + ox * R6 + oy * R7 + oz * R8;
        bool inb = (px > -1.f) & (px < 64.f) & (py > -1.f) & (py < 64.f)
                 & (pz > -1.f) & (pz < 64.f);
        if (inb) a = fmaf(s_psf[k], trilin_gather_bf(vin, px, py, pz), a);
    }
    float outv = SUB ? (slc[gid] - a) : a;
    gp[s * GP_SLC + (h + 1) * GP_ROW + (w + 1)] = outv;
}

// ---------------- block reduce -> one atomic (256-thr kernels) ----------------
__device__ __forceinline__ void block_reduce_atomic(float v, float* dst) {
#pragma unroll
    for (int off = 32; off > 0; off >>= 1) v += __shfl_down(v, off, 64);
    __shared__ float s_red[4];
    int lane = threadIdx.x & 63, wid = threadIdx.x >> 6;
    if (lane == 0) s_red[wid] = v;
    __syncthreads();
    if (threadIdx.x == 0) atomicAdd(dst, s_red[0] + s_red[1] + s_red[2] + s_red[3]);
}

// ---------------------------------------------------------------
// Adjoint At: wave-uniform slice -> scalar/broadcast table loads.
// Block = 512 thr = 8 waves; wave = 64 cols (one full y-row) x 1 slice.
// blockIdx: Yb = b>>3, split = b&7; slice = split*8 + wave.
// No LDS table staging. 6-slot register z-window, scalar tent.
// Writes partial volume per split (8 partials).
// ---------------------------------------------------------------
__global__ __launch_bounds__(512, 2) void k_atv(const float* __restrict__ g,
                                                float* __restrict__ part,
                                                const float* __restrict__ tab) {
    __shared__ float cols[64][COL_PAD];     // 17.2 KB
    int tid = threadIdx.x;
    {
        float4* c4 = (float4*)&cols[0][0];  // 64*67 = 4288 floats = 1072 float4
#pragma unroll
        for (int i = 0; i < 3; ++i) {
            int j = tid + i * 512;
            if (j < 1072) c4[j] = make_float4(0.f, 0.f, 0.f, 0.f);
        }
    }
    __syncthreads();

    int Yb    = blockIdx.x >> 3;
    int split = blockIdx.x & 7;
    int lane  = tid & 63;               // col x
    int wave  = tid >> 6;               // 0..7
    int s = __builtin_amdgcn_readfirstlane(split * 8 + wave);  // wave-uniform
    float X = (float)lane, Y = (float)Yb;

    const float* tb = tab + s * 27 * 16;
    int gbase = s * GP_SLC;

    // window base from center tap (k=13, ox=oy=oz=0)
    const float* ec = tb + 13 * 16;
    float4 ce0 = *(const float4*)(ec);
    float4 ce2 = *(const float4*)(ec + 8);
    float4 ce3 = *(const float4*)(ec + 12);
    float rxc = X - ce2.z, ryc = Y - ce2.w;
    float wsc = ce0.x * rxc + ce0.z * ryc;
    float hsc = ce0.y * rxc + ce0.w * ryc;
    float pzc = fmaf(wsc, ce2.x, fmaf(hsc, ce2.y, ce3.x));
    float basef = floorf(pzc) - 2.f;
    int   basei = (int)basef;

    float acc[WIN];
#pragma unroll
    for (int j = 0; j < WIN; ++j) acc[j] = 0.f;

#pragma unroll 3
    for (int k = 0; k < 27; ++k) {
        const float* e = tb + k * 16;
        float4 e0 = *(const float4*)(e);
        float4 e1 = *(const float4*)(e + 4);
        float4 e2 = *(const float4*)(e + 8);
        float4 e3 = *(const float4*)(e + 12);
        float rx = X - e2.z, ry = Y - e2.w;        // X - Cx, Y - Cy
        float ws = e0.x * rx + e0.z * ry;
        float hs = e0.y * rx + e0.w * ry;
        float w0f = __builtin_amdgcn_fmed3f(floorf(ws), -1.f, 63.f);
        float h0f = __builtin_amdgcn_fmed3f(floorf(hs), -1.f, 63.f);
        int wA = (int)w0f, hA = (int)h0f;
        float Ux = e1.x, Uy = e1.y, Vx = e1.z, Vy = e1.w;
        float Uz = e2.x, Vz = e2.y;
        float Czb = e3.x - basef;
        float psfk = e3.y;
        float Cxr = -rx, Cyr = -ry;                // C - voxel(x,y)
        int colbase = gbase + wA + 1;
#pragma unroll
        for (int dh = 0; dh < 2; ++dh) {
            float fh = h0f + (float)dh;
            float tx  = fmaf(fh, Vx, Cxr);
            float ty  = fmaf(fh, Vy, Cyr);
            float tzb = fmaf(fh, Vz, Czb);
            int rowoff = colbase + (hA + 1 + dh) * GP_ROW;
#pragma unroll
            for (int dw = 0; dw < 2; ++dw) {
                float fw = w0f + (float)dw;
                float ddx = fmaf(fw, Ux, tx);      // px - X
                float ddy = fmaf(fw, Uy, ty);      // py - Y
                float wx = fmaxf(1.f - fabsf(ddx), 0.f);
                float wy = fmaxf(1.f - fabsf(ddy), 0.f);
                float gv = g[rowoff + dw];         // padded: OOB -> 0
                float val = wx * wy * psfk * gv;
                float prel = fmaf(fw, Uz, tzb);    // pz - basef
#pragma unroll
                for (int j = 0; j < WIN; ++j) {
                    float t = fmaxf(0.f, 1.f - fabsf(prel - (float)j));
                    acc[j] = fmaf(val, t, acc[j]);
                }
            }
        }
    }

#pragma unroll
    for (int j = 0; j < WIN; ++j) {
        int zj = basei + j;
        int okz = ((unsigned)zj < 64u);
        int zc = min(max(zj, 0), 63);
        atomicAdd(&cols[lane][zc], okz ? acc[j] : 0.f);
    }
    __syncthreads();

    // write partial: full y-row, 64 cols x 64 z = 4096 voxels
    float* pout = part + split * NVOX + (Yb << 6);
#pragma unroll
    for (int i = 0; i < 8; ++i) {
        int j = tid + i * 512;
        int z = j >> 6, x = j & 63;
        pout[(z << 12) + x] = cols[x][z];
    }
}

// ---------------- partial-sum consumers & CG updates ----------------

__device__ __forceinline__ float sum8(const float* __restrict__ part, int i) {
    float a = 0.f;
#pragma unroll
    for (int j = 0; j < SPLIT; ++j) a += part[j * NVOX + i];
    return a;
}

// r = p = sum8(part); scal[0] += r.r
__global__ __launch_bounds__(256) void k_residual8(const float* __restrict__ part,
                                                   float* __restrict__ r,
                                                   float* __restrict__ p,
                                                   float* __restrict__ scal) {
    int i = blockIdx.x * 256 + threadIdx.x;
    float rv = sum8(part, i);
    r[i] = rv;
    p[i] = rv;
    block_reduce_atomic(rv * rv, &scal[0]);
}

// Ap = sum8(part); dst += p.Ap
__global__ __launch_bounds__(256) void k_dot_reduce8(const float* __restrict__ part,
                                                     const float* __restrict__ p,
                                                     float* __restrict__ Ap,
                                                     float* __restrict__ dst) {
    int i = blockIdx.x * 256 + threadIdx.x;
    float apv = sum8(part, i);
    Ap[i] = apv;
    block_reduce_atomic(p[i] * apv, dst);
}

// dst += p . sum8(part)
__global__ __launch_bounds__(256) void k_dot8(const float* __restrict__ part,
                                              const float* __restrict__ p,
                                              float* __restrict__ dst) {
    int i = blockIdx.x * 256 + threadIdx.x;
    block_reduce_atomic(p[i] * sum8(part, i), dst);
}

// alpha = scal[0]/scal[1]; x_out = x_in + alpha p; r -= alpha Ap; scal[2] += r.r
__global__ __launch_bounds__(256) void k_update_xr(const float* __restrict__ x_in,
                                                   float* __restrict__ x_out,
                                                   float* __restrict__ r,
                                                   const float* __restrict__ p,
                                                   const float* __restrict__ Ap,
                                                   float* __restrict__ scal) {
    int i = blockIdx.x * 256 + threadIdx.x;
    float alpha = scal[0] / scal[1];
    x_out[i] = fmaf(alpha, p[i], x_in[i]);
    float rv = fmaf(-alpha, Ap[i], r[i]);
    r[i] = rv;
    block_reduce_atomic(rv * rv, &scal[2]);
}

__global__ __launch_bounds__(256) void k_update_p(float* __restrict__ p,
                                                  const float* __restrict__ r,
                                                  const float* __restrict__ scal) {
    int i = blockIdx.x * 256 + threadIdx.x;
    float beta = scal[2] / scal[0];
    p[i] = fmaf(beta, p[i], r[i]);
}

__global__ __launch_bounds__(256) void k_final(const float* __restrict__ x,
                                               const float* __restrict__ p,
                                               const float* __restrict__ scal,
                                               float* __restrict__ out) {
    int i = blockIdx.x * 256 + threadIdx.x;
    float alpha = scal[2] / scal[3];
    float v = fmaf(alpha, p[i], x[i]);
    out[i] = v > 0.f ? v : 0.f;
}

extern "C" void kernel_launch(void* const* d_in, const int* in_sizes, int n_in,
                              void* d_out, int out_size, void* d_ws, size_t ws_size,
                              hipStream_t stream) {
    const float* transforms = (const float*)d_in[0];
    const float* slices     = (const float*)d_in[1];
    const float* volume     = (const float*)d_in[2];
    const float* psf        = (const float*)d_in[3];
    float* out = (float*)d_out;

    // layout: tab | gbuf(padded) | scal | part(8) | x | r | p | Ap  (~14 MB)
    float* tab    = (float*)d_ws;             // NTAB*16 = 27648
    float* gbuf   = tab    + NTAB * 16;       // GP_TOT = 287232 (zero-padded g)
    float* scal   = gbuf   + GP_TOT;          // 4 floats (+pad to 8)
    float* part   = scal   + 8;               // 8 * NVOX
    float* vol_x  = part   + SPLIT * NVOX;
    float* vol_r  = vol_x  + NVOX;
    float* vol_p  = vol_r  + NVOX;
    float* Ap     = vol_p  + NVOX;

    const int ablk = 64 * SPLIT;              // 512 (k_atv: y-row x split)
    const int fblk = NPIX / 256;              // 1024 (k_a: 1 thr/pixel)
    const int vblk = NVOX / 256;              // 16

    // one memset covers padded-g borders AND scal
    hipMemsetAsync(gbuf, 0, (GP_TOT + 8) * sizeof(float), stream);

    k_setup<<<(NTAB + 255) / 256, 256, 0, stream>>>(transforms, psf, tab);

    // r0 = At(slices - A(x0)); p = r0; rr0
    k_a<true><<<fblk, 256, 0, stream>>>(volume, gbuf, transforms, psf, slices);
    k_atv<<<ablk, 512, 0, stream>>>(gbuf, part, tab);
    k_residual8<<<vblk, 256, 0, stream>>>(part, vol_r, vol_p, scal);

    // iter 0: Ap = AtA(p); alpha; x,r updates; beta; p update
    k_a<false><<<fblk, 256, 0, stream>>>(vol_p, gbuf, transforms, psf, nullptr);
    k_atv<<<ablk, 512, 0, stream>>>(gbuf, part, tab);
    k_dot_reduce8<<<vblk, 256, 0, stream>>>(part, vol_p, Ap, &scal[1]);
    k_update_xr<<<vblk, 256, 0, stream>>>(volume, vol_x, vol_r, vol_p, Ap, scal);
    k_update_p<<<vblk, 256, 0, stream>>>(vol_p, vol_r, scal);

    // iter 1: pAp1; out = relu(x + alpha p)
    k_a<false><<<fblk, 256, 0, stream>>>(vol_p, gbuf, transforms, psf, nullptr);
    k_atv<<<ablk, 512, 0, stream>>>(gbuf, part, tab);
    k_dot8<<<vblk, 256, 0, stream>>>(part, vol_p, &scal[3]);
    k_final<<<vblk, 256, 0, stream>>>(vol_x, vol_p, scal, out);
}